// Round 17
// baseline (233.241 us; speedup 1.0000x reference)
//
#include <hip/hip_runtime.h>
#include <math.h>

#define DIMM  512
#define NSEQ  1024
#define NHEAD 8
#define DH    64
#define DFF   2048
#define NVOC  32000
#define NDEPTH 2
#define VCENTER 32.0f
#define KVB   64
#define QBLK  32
#define QKOFF ((size_t)NHEAD * NSEQ * DH)   // 524288 elements
#define FLASH_BLOCKS (NSEQ / QBLK * NHEAD)  // 256
#define CONV_ROWS_PER_LAYER (NVOC / NDEPTH) // 16000
#define CONV_BLOCKS (CONV_ROWS_PER_LAYER / 64)  // 250
#define WCONV_PER_LAYER (3 * DIMM + DIMM + DFF + DIMM)  // 4608 rows/layer

typedef __attribute__((ext_vector_type(8))) __bf16 bf16x8;
typedef __attribute__((ext_vector_type(4))) __bf16 bf16x4;
typedef __attribute__((ext_vector_type(4))) float f32x4;

__device__ __forceinline__ void g2l16(const void* g, void* l) {
    __builtin_amdgcn_global_load_lds(
        (const __attribute__((address_space(1))) void*)g,
        (__attribute__((address_space(3))) void*)l, 16, 0, 0);
}

#define WAITV(N) asm volatile("s_waitcnt vmcnt(" #N ")" ::: "memory")

// ---------------------------------------------------------------- one weight row: f32->bf16 (+sumsq)
template<int NTHR>
__device__ __forceinline__ void conv_weight_row(
    int bid, int l,
    const float* __restrict__ qkv_w, const float* __restrict__ attn_out_w,
    const float* __restrict__ ff_in_w, const float* __restrict__ ff_out_w,
    __bf16* __restrict__ wq16, __bf16* __restrict__ wa16,
    __bf16* __restrict__ wfi16, __bf16* __restrict__ wfo16,
    float* __restrict__ wsq_qkv, float* __restrict__ wsq_ff, float* red) {
    const int tid = threadIdx.x;
    const float* src; __bf16* dst; float* ssq; int K = DIMM; int row;
    if (bid < 3 * DIMM) {
        row = l * 3 * DIMM + bid; src = qkv_w; dst = wq16; ssq = wsq_qkv;
    } else if ((bid -= 3 * DIMM) < DIMM) {
        row = l * DIMM + bid; src = attn_out_w; dst = wa16; ssq = nullptr;
    } else if ((bid -= DIMM) < DFF) {
        row = l * DFF + bid; src = ff_in_w; dst = wfi16; ssq = wsq_ff;
    } else {
        bid -= DFF; row = l * DIMM + bid; src = ff_out_w; dst = wfo16; ssq = nullptr; K = DFF;
    }
    const float* s = src + (size_t)row * K;
    __bf16* d = dst + (size_t)row * K;
    float ss = 0.f;
    for (int j = tid; j < K; j += NTHR) {
        float v = s[j];
        d[j] = (__bf16)v;
        ss += v * v;
    }
    #pragma unroll
    for (int off = 32; off; off >>= 1) ss += __shfl_down(ss, off, 64);
    if ((tid & 63) == 0) red[tid >> 6] = ss;
    __syncthreads();
    if (tid == 0 && ssq) {
        float t = red[0] + red[1];
        if (NTHR == 256) t += red[2] + red[3];
        ssq[row] = t;
    }
}

// ---------------------------------------------------------------- layer-0 weight conversions + embed/rms (fused grid)
__launch_bounds__(256)
__global__ void conv_embed(const float* __restrict__ qkv_w, const float* __restrict__ attn_out_w,
                           const float* __restrict__ ff_in_w, const float* __restrict__ ff_out_w,
                           __bf16* __restrict__ wq16, __bf16* __restrict__ wa16,
                           __bf16* __restrict__ wfi16, __bf16* __restrict__ wfo16,
                           float* __restrict__ wsq_qkv, float* __restrict__ wsq_ff,
                           const int* __restrict__ tokens, const float* __restrict__ temb,
                           const float* __restrict__ pemb, const float* __restrict__ gamma,
                           float* __restrict__ x, __bf16* __restrict__ y,
                           float* __restrict__ xs) {
    const int tid = threadIdx.x;
    __shared__ float red[4];

    if (blockIdx.x >= WCONV_PER_LAYER) {
        // ---- embed + layer0 rmsnorm path
        const int i = blockIdx.x - WCONV_PER_LAYER;
        int tok = tokens[i];
        const float* e = temb + (size_t)tok * DIMM;
        const float* pp = pemb + (size_t)i * DIMM;
        float v0 = e[tid] + pp[tid];
        float v1 = e[tid + 256] + pp[tid + 256];
        x[(size_t)i * DIMM + tid]       = v0;
        x[(size_t)i * DIMM + tid + 256] = v1;
        float ss = v0 * v0 + v1 * v1;
        #pragma unroll
        for (int off = 32; off; off >>= 1) ss += __shfl_down(ss, off, 64);
        if ((tid & 63) == 0) red[tid >> 6] = ss;
        __syncthreads();
        float tot = red[0] + red[1] + red[2] + red[3];
        float scale = 22.627416997969522f / fmaxf(sqrtf(tot), 1e-12f);
        float y0 = v0 * scale * (gamma[tid] + 1.0f);
        float y1 = v1 * scale * (gamma[tid + 256] + 1.0f);
        y[(size_t)i * DIMM + tid]       = (__bf16)y0;
        y[(size_t)i * DIMM + tid + 256] = (__bf16)y1;
        float s2 = y0 * y0 + y1 * y1;
        __syncthreads();
        #pragma unroll
        for (int off = 32; off; off >>= 1) s2 += __shfl_down(s2, off, 64);
        if ((tid & 63) == 0) red[tid >> 6] = s2;
        __syncthreads();
        if (tid == 0) xs[i] = red[0] + red[1] + red[2] + red[3];
        return;
    }

    conv_weight_row<256>(blockIdx.x, 0, qkv_w, attn_out_w, ff_in_w, ff_out_w,
                         wq16, wa16, wfi16, wfo16, wsq_qkv, wsq_ff, red);
}

// ---------------------------------------------------------------- split-K reduce + residual + rmsnorm (fused)
template<int S>
__launch_bounds__(256)
__global__ void rms_red(const float* __restrict__ parts, float* __restrict__ x,
                        const float* __restrict__ gamma,
                        __bf16* __restrict__ y, float* __restrict__ xs) {
    int i = blockIdx.x;
    int tid = threadIdx.x;
    float* xr = x + (size_t)i * DIMM;
    float v0 = xr[tid], v1 = xr[tid + 256];
    #pragma unroll
    for (int s = 0; s < S; s++) {
        const float* pr = parts + (size_t)s * NSEQ * DIMM + (size_t)i * DIMM;
        v0 += pr[tid];
        v1 += pr[tid + 256];
    }
    xr[tid] = v0;
    xr[tid + 256] = v1;
    float ss = v0 * v0 + v1 * v1;
    __shared__ float red[4];
    #pragma unroll
    for (int off = 32; off; off >>= 1) ss += __shfl_down(ss, off, 64);
    if ((tid & 63) == 0) red[tid >> 6] = ss;
    __syncthreads();
    float tot = red[0] + red[1] + red[2] + red[3];
    float scale = 22.627416997969522f / fmaxf(sqrtf(tot), 1e-12f);
    float y0 = v0 * scale * (gamma[tid] + 1.0f);
    float y1 = v1 * scale * (gamma[tid + 256] + 1.0f);
    y[(size_t)i * DIMM + tid]       = (__bf16)y0;
    y[(size_t)i * DIMM + tid + 256] = (__bf16)y1;
    float s2 = y0 * y0 + y1 * y1;
    __syncthreads();
    #pragma unroll
    for (int off = 32; off; off >>= 1) s2 += __shfl_down(s2, off, 64);
    if ((tid & 63) == 0) red[tid >> 6] = s2;
    __syncthreads();
    if (tid == 0) xs[i] = red[0] + red[1] + red[2] + red[3];
}

enum { MODE_LINEAR = 0, MODE_CDIST = 1, MODE_FFGELU = 2, MODE_LOGITS = 3 };

template<int MODE>
__device__ __forceinline__ void write_elem(void* Cout, int r, int c, int M, float dot,
                                           float xsr, const float* __restrict__ ws,
                                           const float* __restrict__ bias) {
    if (MODE == MODE_LINEAR) {
        ((float*)Cout)[(size_t)r * M + c] = dot;
    } else if (MODE == MODE_FFGELU) {
        float d2 = xsr + ws[c] - 2.0f * dot;
        float hh = -d2 + bias[c];
        float v = 0.5f * hh * (1.0f + erff(hh * 0.70710678118654752f));
        ((__bf16*)Cout)[(size_t)r * M + c] = (__bf16)v;
    }
}

// ---------------------------------------------------------------- logits GEMM, 128x256 tile, 512 thr
// 6 chunk-buffers (3 pairs), two BK=32 chunks/phase, counted vmcnt.
// Epilogue: acc -> swizzled f32 LDS tile -> coalesced nontemporal float4 row writes.
__launch_bounds__(512)
__global__ void gemm_logits(const __bf16* __restrict__ A, const __bf16* __restrict__ W,
                            const float* __restrict__ xs, const float* __restrict__ ws,
                            float* __restrict__ out) {
    __shared__ __align__(16) char smem[49152 + 98304];   // As(48K) | Bs(96K); reused as f32 tile(128K)
    __bf16* As = (__bf16*)smem;
    __bf16* Bs = (__bf16*)(smem + 49152);
    float* tile = (float*)smem;
    const int tid = threadIdx.x;            // 0..511
    const int lane = tid & 63;
    const int wv = tid >> 6;                // 0..7
    const int wr = wv >> 2, wc = wv & 3;    // 2 x 4 waves

    int id = blockIdx.x;                    // 1000 blocks
    id = (id & 7) * 125 + (id >> 3);
    const int row0 = (id & 7) * 128;
    const int col0 = (id >> 3) * 256;

    const int scol = ((tid & 3) ^ ((tid >> 3) & 3)) * 8;
    const __bf16* gA = A + (size_t)(row0 + (tid >> 2)) * DIMM + scol;
    const __bf16* gB = W + (size_t)(col0 + (tid >> 2)) * DIMM + scol;
    const int lrow = lane & 15;
    const int l4 = lane >> 4;
    const int slot = (l4 ^ ((lrow >> 1) & 3)) * 8;

    auto stageChunk = [&](int k0, int b) {       // 3 loads/thread/chunk
        g2l16(gA + k0,                      As + b * 4096 + tid * 8);
        g2l16(gB + k0,                      Bs + b * 8192 + tid * 8);
        g2l16(gB + (size_t)128 * DIMM + k0, Bs + b * 8192 + 4096 + tid * 8);
    };

    f32x4 acc[4][4] = {};
    const int nP = DIMM >> 6;               // 8 pair-phases
    stageChunk(0, 0);  stageChunk(32, 1);
    stageChunk(64, 2); stageChunk(96, 3);
    int pb = 0;
    for (int p = 0; p < nP; p++) {
        if (p < nP - 1) WAITV(6); else WAITV(0);
        __builtin_amdgcn_s_barrier();
        __builtin_amdgcn_sched_barrier(0);
        if (p + 2 < nP) {
            int nb = pb + 2; if (nb >= 3) nb -= 3;
            stageChunk((p + 2) << 6,        nb * 2);
            stageChunk(((p + 2) << 6) + 32, nb * 2 + 1);
        }
        #pragma unroll
        for (int half = 0; half < 2; half++) {
            const int b = pb * 2 + half;
            bf16x8 af[4], bfr[4];
            #pragma unroll
            for (int m = 0; m < 4; m++)
                af[m] = *(const bf16x8*)(As + b * 4096 + (wr * 64 + m * 16 + lrow) * 32 + slot);
            #pragma unroll
            for (int n = 0; n < 4; n++)
                bfr[n] = *(const bf16x8*)(Bs + b * 8192 + (wc * 64 + n * 16 + lrow) * 32 + slot);
            #pragma unroll
            for (int m = 0; m < 4; m++)
                #pragma unroll
                for (int n = 0; n < 4; n++)
                    acc[m][n] = __builtin_amdgcn_mfma_f32_16x16x32_bf16(af[m], bfr[n], acc[m][n], 0, 0, 0);
        }
        if (++pb == 3) pb = 0;
    }
    __syncthreads();   // staging LDS dead; safe to reuse as f32 tile

    #pragma unroll
    for (int m = 0; m < 4; m++)
        #pragma unroll
        for (int j = 0; j < 4; j++) {
            const int rl = wr * 64 + m * 16 + l4 * 4 + j;
            const float xsr = xs[row0 + rl];
            const int sw = ((rl >> 2) & 3) << 2;
            #pragma unroll
            for (int n = 0; n < 4; n++) {
                const int cl = wc * 64 + n * 16 + lrow;
                tile[rl * 256 + (cl ^ sw)] = -(xsr + ws[col0 + cl] - 2.0f * acc[m][n][j]);
            }
        }
    __syncthreads();

    #pragma unroll
    for (int jj = 0; jj < 16; jj++) {
        const int f = jj * 2048 + tid * 4;
        const int rr = f >> 8, cc = f & 255;
        const int sw = ((rr >> 2) & 3) << 2;
        f32x4 v = *(const f32x4*)&tile[rr * 256 + (cc ^ sw)];
        __builtin_nontemporal_store(v, (f32x4*)&out[(size_t)(row0 + rr) * NVOC + col0 + cc]);
    }
}

// ---------------------------------------------------------------- MFMA GEMM, 64x64 tile
// 6 chunk-buffers (3 pairs), two BK=32 chunks per barrier phase, counted vmcnt.
template<int MODE>
__launch_bounds__(256)
__global__ void gemm64(const __bf16* __restrict__ A, const __bf16* __restrict__ W,
                       const float* __restrict__ xs, const float* __restrict__ ws,
                       const float* __restrict__ bias,
                       void* __restrict__ Cout, int K, int Kstr, int M,
                       float* __restrict__ ksout) {
    __shared__ __align__(16) __bf16 As[6 * 64 * 32];   // 24 KB
    __shared__ __align__(16) __bf16 Bs[6 * 64 * 32];   // 24 KB
    __shared__ float ksred[2][64];
    const int tid = threadIdx.x;
    const int lane = tid & 63;
    const int wv = tid >> 6;
    const int wr = wv >> 1, wc = wv & 1;

    const int gx = gridDim.x;
    const int total = gx * gridDim.y;
    int id = blockIdx.y * gx + blockIdx.x;
    id = (id & 7) * (total >> 3) + (id >> 3);
    const int bx = id % gx;
    const int by = id / gx;
    const int row0 = by * 64;
    const int col0 = bx * 64;
    const size_t zoff = (size_t)blockIdx.z * K;
    float* Cz = (float*)Cout + (size_t)blockIdx.z * NSEQ * M;

    const int scol = (((tid & 3) ^ ((tid >> 3) & 3))) * 8;
    const __bf16* gA = A + (size_t)(row0 + (tid >> 2)) * Kstr + scol + zoff;
    const __bf16* gB = W + (size_t)(col0 + (tid >> 2)) * Kstr + scol + zoff;
    const int lrow = lane & 15;
    const int l4 = lane >> 4;
    const int slot = (l4 ^ ((lrow >> 1) & 3)) * 8;

    auto stageChunk = [&](int k0, int b) {   // 2 loads/thread/chunk
        g2l16(gA + k0, &As[b * 2048 + tid * 8]);
        g2l16(gB + k0, &Bs[b * 2048 + tid * 8]);
    };

    f32x4 acc[2][2] = {};
    const int nP = K >> 6;          // pair-phases
    stageChunk(0, 0);  stageChunk(32, 1);
    stageChunk(64, 2); stageChunk(96, 3);
    int pb = 0;
    for (int p = 0; p < nP; p++) {
        if (p < nP - 1) WAITV(4); else WAITV(0);
        __builtin_amdgcn_s_barrier();
        __builtin_amdgcn_sched_barrier(0);
        if (p + 2 < nP) {
            int nb = pb + 2; if (nb >= 3) nb -= 3;
            stageChunk((p + 2) << 6,        nb * 2);
            stageChunk(((p + 2) << 6) + 32, nb * 2 + 1);
        }
        #pragma unroll
        for (int half = 0; half < 2; half++) {
            const int b = pb * 2 + half;
            bf16x8 af[2], bfr[2];
            #pragma unroll
            for (int m = 0; m < 2; m++)
                af[m] = *(const bf16x8*)&As[b * 2048 + (wr * 32 + m * 16 + lrow) * 32 + slot];
            #pragma unroll
            for (int n = 0; n < 2; n++)
                bfr[n] = *(const bf16x8*)&Bs[b * 2048 + (wc * 32 + n * 16 + lrow) * 32 + slot];
            #pragma unroll
            for (int m = 0; m < 2; m++)
                #pragma unroll
                for (int n = 0; n < 2; n++)
                    acc[m][n] = __builtin_amdgcn_mfma_f32_16x16x32_bf16(af[m], bfr[n], acc[m][n], 0, 0, 0);
        }
        if (++pb == 3) pb = 0;
    }

    const int r_base = row0 + wr * 32 + (lane >> 4) * 4;
    const int c_base = col0 + wc * 32 + (lane & 15);

    if (MODE == MODE_CDIST) {
        const int sec = col0 >> 9;          // 0=q,1=k,2=v (uniform per block)
        const int h = (col0 >> 6) & 7;
        __bf16* Qc = (__bf16*)Cout;
        float pk[2][4];
        #pragma unroll
        for (int m = 0; m < 2; m++)
            #pragma unroll
            for (int j = 0; j < 4; j++) {
                const int r = r_base + m * 16 + j;
                const float xsr = xs[r];
                pk[m][j] = 0.f;
                #pragma unroll
                for (int n = 0; n < 2; n++) {
                    const int c = c_base + n * 16;
                    float d2 = xsr + ws[c] - 2.0f * acc[m][n][j];
                    float v = sqrtf(fmaxf(d2, 0.0f)) - VCENTER;
                    __bf16 bv = (__bf16)v;
                    const int d = c & 63;
                    if (sec == 0)      Qc[((size_t)h * NSEQ + r) * DH + d] = bv;
                    else if (sec == 1) Qc[QKOFF + ((size_t)h * NSEQ + r) * DH + d] = bv;
                    else               Qc[2 * QKOFF + ((size_t)h * DH + d) * NSEQ + r] = bv;
                    float fv = (float)bv;
                    pk[m][j] += fv * fv;
                }
            }
        if (sec == 1) {
            #pragma unroll
            for (int m = 0; m < 2; m++)
                #pragma unroll
                for (int j = 0; j < 4; j++) {
                    float v = pk[m][j];
                    #pragma unroll
                    for (int off = 1; off < 16; off <<= 1) v += __shfl_xor(v, off, 64);
                    if (lrow == 0) ksred[wc][wr * 32 + m * 16 + l4 * 4 + j] = v;
                }
            __syncthreads();
            if (tid < 64)
                ksout[(size_t)h * NSEQ + row0 + tid] = ksred[0][tid] + ksred[1][tid];
        }
    } else {
        #pragma unroll
        for (int m = 0; m < 2; m++)
            #pragma unroll
            for (int j = 0; j < 4; j++) {
                const int r = r_base + m * 16 + j;
                const float xsr = (MODE == MODE_LINEAR) ? 0.f : xs[r];
                #pragma unroll
                for (int n = 0; n < 2; n++)
                    write_elem<MODE>(Cz, r, c_base + n * 16, M, acc[m][n][j], xsr, ws, bias);
            }
    }
}

// ---------------------------------------------------------------- flash attention + temb conversion + (layer-0 only)
// next-layer weight conversion, all in one grid:
// [0,256): flash; [256,506): temb rows; [506, 506+4608): layer-1 weight rows
__launch_bounds__(128)
__global__ void flash_attn(const __bf16* __restrict__ Qc, const __bf16* __restrict__ Kc,
                           const __bf16* __restrict__ VcT, const float* __restrict__ ks,
                           __bf16* __restrict__ O,
                           const float* __restrict__ temb, __bf16* __restrict__ temb16,
                           float* __restrict__ wsq_temb, int conv_row0,
                           const float* __restrict__ qkv_w, const float* __restrict__ attn_out_w,
                           const float* __restrict__ ff_in_w, const float* __restrict__ ff_out_w,
                           __bf16* __restrict__ wq16, __bf16* __restrict__ wa16,
                           __bf16* __restrict__ wfi16, __bf16* __restrict__ wfo16,
                           float* __restrict__ wsq_qkv, float* __restrict__ wsq_ff) {
    const int tid = threadIdx.x, lane = tid & 63, wv = tid >> 6;

    if (blockIdx.x >= FLASH_BLOCKS + CONV_BLOCKS) {
        // ---- next-layer weight conversion (present only in layer-0 launch)
        __shared__ float redc[2];
        conv_weight_row<128>(blockIdx.x - FLASH_BLOCKS - CONV_BLOCKS, 1,
                             qkv_w, attn_out_w, ff_in_w, ff_out_w,
                             wq16, wa16, wfi16, wfo16, wsq_qkv, wsq_ff, redc);
        return;
    }
    if (blockIdx.x >= FLASH_BLOCKS) {
        // ---- temb conversion path: 64 rows/block (nt-stores: no reuse before logits)
        const int base = conv_row0 + (blockIdx.x - FLASH_BLOCKS) * 64;
        for (int it = 0; it < 32; it++) {
            const int row = base + it * 2 + wv;
            const float* src = temb + (size_t)row * DIMM;
            float4 a = ((const float4*)src)[lane];
            float4 b2 = ((const float4*)src)[lane + 64];
            float ss = a.x * a.x + a.y * a.y + a.z * a.z + a.w * a.w
                     + b2.x * b2.x + b2.y * b2.y + b2.z * b2.z + b2.w * b2.w;
            bf16x4 oa, ob;
            oa.x = (__bf16)a.x;  oa.y = (__bf16)a.y;  oa.z = (__bf16)a.z;  oa.w = (__bf16)a.w;
            ob.x = (__bf16)b2.x; ob.y = (__bf16)b2.y; ob.z = (__bf16)b2.z; ob.w = (__bf16)b2.w;
            __builtin_nontemporal_store(oa, (bf16x4*)&temb16[(size_t)row * DIMM + lane * 4]);
            __builtin_nontemporal_store(ob, (bf16x4*)&temb16[(size_t)row * DIMM + 256 + lane * 4]);
            #pragma unroll
            for (int off = 32; off; off >>= 1) ss += __shfl_down(ss, off, 64);
            if (lane == 0) wsq_temb[row] = ss;
        }
        return;
    }

    __shared__ __align__(16) __bf16 Qs[QBLK * 64];
    __shared__ __align__(16) __bf16 Ks[2][64 * 64];
    __shared__ __align__(16) __bf16 Vs[2][64 * 64];
    __shared__ __align__(16) __bf16 Ps[2][16 * 64];
    __shared__ float kss[2][64];
    const int h = blockIdx.x >> 5, q0 = (blockIdx.x & 31) * QBLK;
    const int l15 = lane & 15, l4 = lane >> 4;

    #pragma unroll
    for (int pass = 0; pass < 2; pass++) {
        int gl = tid + pass * 128, r = gl >> 3, gs = (gl & 7) ^ (r & 7);
        g2l16(Qc + ((size_t)h * NSEQ + q0 + r) * DH + gs * 8, &Qs[gl * 8]);
    }
    auto stage = [&](int c, int buf) {
        const int kv0 = c * KVB;
        #pragma unroll
        for (int pass = 0; pass < 4; pass++) {
            int gl = tid + pass * 128, r = gl >> 3, gs = (gl & 7) ^ (r & 7);
            g2l16(Kc + ((size_t)h * NSEQ + kv0 + r) * DH + gs * 8, &Ks[buf][gl * 8]);
            g2l16(VcT + ((size_t)h * DH + r) * NSEQ + kv0 + gs * 8, &Vs[buf][gl * 8]);
        }
        if (tid < KVB) kss[buf][tid] = ks[(size_t)h * NSEQ + c * KVB + tid];
    };
    stage(0, 0);
    __syncthreads();

    bf16x8 qf[2];
    #pragma unroll
    for (int s = 0; s < 2; s++) {
        int row = wv * 16 + l15;
        int g = (l4 + 4 * s) ^ (row & 7);
        qf[s] = *(const bf16x8*)&Qs[row * 64 + g * 8];
    }

    float m_j[4], l_j[4];
    f32x4 o_[4] = {};
    #pragma unroll
    for (int j = 0; j < 4; j++) { m_j[j] = -1e30f; l_j[j] = 0.f; }

    for (int c = 0; c < NSEQ / KVB; c++) {
        const int b = c & 1;
        if (c + 1 < NSEQ / KVB) stage(c + 1, b ^ 1);

        f32x4 sa[4] = {};
        #pragma unroll
        for (int s = 0; s < 2; s++) {
            bf16x8 kf[4];
            #pragma unroll
            for (int n = 0; n < 4; n++) {
                int row = n * 16 + l15;
                int g = (l4 + 4 * s) ^ (row & 7);
                kf[n] = *(const bf16x8*)&Ks[b][row * 64 + g * 8];
            }
            #pragma unroll
            for (int n = 0; n < 4; n++)
                sa[n] = __builtin_amdgcn_mfma_f32_16x16x32_bf16(qf[s], kf[n], sa[n], 0, 0, 0);
        }
        float ksv[4];
        #pragma unroll
        for (int n = 0; n < 4; n++) ksv[n] = kss[b][n * 16 + l15];

        float scale[4];
        #pragma unroll
        for (int j = 0; j < 4; j++) {
            float mx = -1e30f;
            #pragma unroll
            for (int n = 0; n < 4; n++) {
                float sv = sa[n][j] * 0.25f - ksv[n] * 0.125f;
                sa[n][j] = sv;
                mx = fmaxf(mx, sv);
            }
            #pragma unroll
            for (int off = 1; off < 16; off <<= 1) mx = fmaxf(mx, __shfl_xor(mx, off, 64));
            float mn = fmaxf(m_j[j], mx);
            scale[j] = expf(m_j[j] - mn);
            m_j[j] = mn;
        }
        #pragma unroll
        for (int j = 0; j < 4; j++) {
            const int row = l4 * 4 + j;
            float ls = 0.f;
            #pragma unroll
            for (int n = 0; n < 4; n++) {
                float pv = expf(sa[n][j] - m_j[j]);
                ls += pv;
                int col = n * 16 + l15;
                Ps[wv][row * 64 + ((((col >> 3) ^ (row & 7)) << 3) | (col & 7))] = (__bf16)pv;
            }
            #pragma unroll
            for (int off = 1; off < 16; off <<= 1) ls += __shfl_xor(ls, off, 64);
            l_j[j] = l_j[j] * scale[j] + ls;
            o_[0][j] *= scale[j]; o_[1][j] *= scale[j];
            o_[2][j] *= scale[j]; o_[3][j] *= scale[j];
        }

        #pragma unroll
        for (int s = 0; s < 2; s++) {
            int g = (l4 + 4 * s) ^ (l15 & 7);
            bf16x8 pf = *(const bf16x8*)&Ps[wv][l15 * 64 + g * 8];
            #pragma unroll
            for (int n = 0; n < 4; n++) {
                int row = n * 16 + l15;
                int gv = (l4 + 4 * s) ^ (row & 7);
                bf16x8 vf = *(const bf16x8*)&Vs[b][row * 64 + gv * 8];
                o_[n] = __builtin_amdgcn_mfma_f32_16x16x32_bf16(pf, vf, o_[n], 0, 0, 0);
            }
        }
        __syncthreads();
    }

    #pragma unroll
    for (int n = 0; n < 4; n++)
        #pragma unroll
        for (int j = 0; j < 4; j++) {
            int row = q0 + wv * 16 + l4 * 4 + j;
            int d = n * 16 + l15;
            O[(size_t)row * DIMM + h * DH + d] = (__bf16)(o_[n][j] / l_j[j] + VCENTER);
        }
}

// ---------------------------------------------------------------- launch
extern "C" void kernel_launch(void* const* d_in, const int* in_sizes, int n_in,
                              void* d_out, int out_size, void* d_ws, size_t ws_size,
                              hipStream_t stream) {
    (void)in_sizes; (void)n_in; (void)out_size; (void)ws_size;
    const int*   tokens      = (const int*)d_in[0];
    const float* temb        = (const float*)d_in[1];
    const float* pemb        = (const float*)d_in[2];
    const float* qkv_w       = (const float*)d_in[3];
    const float* attn_out_w  = (const float*)d_in[4];
    const float* ff_in_w     = (const float*)d_in[5];
    const float* ff_in_b     = (const float*)d_in[6];
    const float* ff_out_w    = (const float*)d_in[7];
    const float* attn_gamma  = (const float*)d_in[8];
    const float* ff_gamma    = (const float*)d_in[9];
    const float* final_gamma = (const float*)d_in[10];
    float* out = (float*)d_out;

    char* p = (char*)d_ws;
    float*  x        = (float*)p;  p += (size_t)NSEQ * DIMM * 4;
    float*  xs       = (float*)p;  p += (size_t)NSEQ * 4;
    float*  wsq_qkv  = (float*)p;  p += (size_t)NDEPTH * 3 * DIMM * 4;
    float*  wsq_ff   = (float*)p;  p += (size_t)NDEPTH * DFF * 4;
    float*  wsq_temb = (float*)p;  p += (size_t)NVOC * 4;
    float*  ksbuf    = (float*)p;  p += (size_t)NHEAD * NSEQ * 4;
    float*  parts    = (float*)p;  p += (size_t)4 * NSEQ * DIMM * 4;   // split-K partials (8 MB)
    __bf16* y16      = (__bf16*)p; p += (size_t)NSEQ * DIMM * 2;
    __bf16* o16      = (__bf16*)p; p += (size_t)NSEQ * DIMM * 2;
    __bf16* Qc       = (__bf16*)p; p += 3 * QKOFF * 2;        // Qc | Kc | VcT
    __bf16* hb16     = (__bf16*)p; p += (size_t)NSEQ * DFF * 2;
    __bf16* wq16     = (__bf16*)p; p += (size_t)NDEPTH * 3 * DIMM * DIMM * 2;
    __bf16* wa16     = (__bf16*)p; p += (size_t)NDEPTH * DIMM * DIMM * 2;
    __bf16* wfi16    = (__bf16*)p; p += (size_t)NDEPTH * DFF * DIMM * 2;
    __bf16* wfo16    = (__bf16*)p; p += (size_t)NDEPTH * DIMM * DFF * 2;
    __bf16* temb16   = (__bf16*)p; p += (size_t)NVOC * DIMM * 2;
    __bf16* Kc  = Qc + QKOFF;
    __bf16* VcT = Qc + 2 * QKOFF;

    conv_embed<<<WCONV_PER_LAYER + NSEQ, 256, 0, stream>>>(
        qkv_w, attn_out_w, ff_in_w, ff_out_w,
        wq16, wa16, wfi16, wfo16, wsq_qkv, wsq_ff,
        tokens, temb, pemb, attn_gamma, x, y16, xs);

    for (int l = 0; l < NDEPTH; l++) {
        const __bf16* qkvw = wq16  + (size_t)l * 3 * DIMM * DIMM;
        const __bf16* aow  = wa16  + (size_t)l * DIMM * DIMM;
        const __bf16* fiw  = wfi16 + (size_t)l * DFF * DIMM;
        const __bf16* fow  = wfo16 + (size_t)l * DIMM * DFF;
        const float*  fib  = ff_in_b + (size_t)l * DFF;
        const float*  next_gamma = (l + 1 < NDEPTH) ? (attn_gamma + (l + 1) * DIMM)
                                                    : final_gamma;

        gemm64<MODE_CDIST><<<dim3(3 * DIMM / 64, NSEQ / 64), 256, 0, stream>>>(
            y16, qkvw, xs, wsq_qkv + l * 3 * DIMM, nullptr, Qc, DIMM, DIMM, 3 * DIMM, ksbuf);
        // layer 0's flash also converts layer-1 weights + first half of temb
        const int flashGrid = FLASH_BLOCKS + CONV_BLOCKS + ((l == 0) ? WCONV_PER_LAYER : 0);
        flash_attn<<<flashGrid, 128, 0, stream>>>(
            Qc, Kc, VcT, ksbuf, o16, temb, temb16, wsq_temb, l * CONV_ROWS_PER_LAYER,
            qkv_w, attn_out_w, ff_in_w, ff_out_w,
            wq16, wa16, wfi16, wfo16, wsq_qkv, wsq_ff);
        gemm64<MODE_LINEAR><<<dim3(DIMM / 64, NSEQ / 64, 2), 256, 0, stream>>>(
            o16, aow, nullptr, nullptr, nullptr, parts, DIMM / 2, DIMM, DIMM, nullptr);
        rms_red<2><<<NSEQ, 256, 0, stream>>>(parts, x, ff_gamma + l * DIMM, y16, xs);

        gemm64<MODE_FFGELU><<<dim3(DFF / 64, NSEQ / 64), 256, 0, stream>>>(
            y16, fiw, xs, wsq_ff + l * DFF, fib, hb16, DIMM, DIMM, DFF, nullptr);
        gemm64<MODE_LINEAR><<<dim3(DIMM / 64, NSEQ / 64, 4), 256, 0, stream>>>(
            hb16, fow, nullptr, nullptr, nullptr, parts, DFF / 4, DFF, DIMM, nullptr);
        rms_red<4><<<NSEQ, 256, 0, stream>>>(parts, x, next_gamma, y16, xs);
    }

    gemm_logits<<<1000, 512, 0, stream>>>(y16, temb16, xs, wsq_temb, out);
}

// Round 19
// 218.485 us; speedup vs baseline: 1.0675x; 1.0675x over previous
//
#include <hip/hip_runtime.h>
#include <math.h>

#define DIMM  512
#define NSEQ  1024
#define NHEAD 8
#define DH    64
#define DFF   2048
#define NVOC  32000
#define NDEPTH 2
#define VCENTER 32.0f
#define KVB   64
#define QBLK  32
#define QKOFF ((size_t)NHEAD * NSEQ * DH)   // 524288 elements
#define FLASH_BLOCKS (NSEQ / QBLK * NHEAD)  // 256
#define CONV_ROWS_PER_LAYER (NVOC / NDEPTH) // 16000
#define CONV_BLOCKS (CONV_ROWS_PER_LAYER / 64)  // 250
#define WCONV_PER_LAYER (3 * DIMM + DIMM + DFF + DIMM)  // 4608 rows/layer

typedef __attribute__((ext_vector_type(8))) __bf16 bf16x8;
typedef __attribute__((ext_vector_type(4))) __bf16 bf16x4;
typedef __attribute__((ext_vector_type(4))) float f32x4;

__device__ __forceinline__ void g2l16(const void* g, void* l) {
    __builtin_amdgcn_global_load_lds(
        (const __attribute__((address_space(1))) void*)g,
        (__attribute__((address_space(3))) void*)l, 16, 0, 0);
}

#define WAITV(N) asm volatile("s_waitcnt vmcnt(" #N ")" ::: "memory")

// ---------------------------------------------------------------- one weight row: f32->bf16 (+sumsq)
template<int NTHR>
__device__ __forceinline__ void conv_weight_row(
    int bid, int l,
    const float* __restrict__ qkv_w, const float* __restrict__ attn_out_w,
    const float* __restrict__ ff_in_w, const float* __restrict__ ff_out_w,
    __bf16* __restrict__ wq16, __bf16* __restrict__ wa16,
    __bf16* __restrict__ wfi16, __bf16* __restrict__ wfo16,
    float* __restrict__ wsq_qkv, float* __restrict__ wsq_ff, float* red) {
    const int tid = threadIdx.x;
    const float* src; __bf16* dst; float* ssq; int K = DIMM; int row;
    if (bid < 3 * DIMM) {
        row = l * 3 * DIMM + bid; src = qkv_w; dst = wq16; ssq = wsq_qkv;
    } else if ((bid -= 3 * DIMM) < DIMM) {
        row = l * DIMM + bid; src = attn_out_w; dst = wa16; ssq = nullptr;
    } else if ((bid -= DIMM) < DFF) {
        row = l * DFF + bid; src = ff_in_w; dst = wfi16; ssq = wsq_ff;
    } else {
        bid -= DFF; row = l * DIMM + bid; src = ff_out_w; dst = wfo16; ssq = nullptr; K = DFF;
    }
    const float* s = src + (size_t)row * K;
    __bf16* d = dst + (size_t)row * K;
    float ss = 0.f;
    for (int j = tid; j < K; j += NTHR) {
        float v = s[j];
        d[j] = (__bf16)v;
        ss += v * v;
    }
    #pragma unroll
    for (int off = 32; off; off >>= 1) ss += __shfl_down(ss, off, 64);
    if ((tid & 63) == 0) red[tid >> 6] = ss;
    __syncthreads();
    if (tid == 0 && ssq) {
        float t = red[0] + red[1];
        if (NTHR == 256) t += red[2] + red[3];
        ssq[row] = t;
    }
}

// ---------------------------------------------------------------- layer-0 weight conversions + embed/rms (fused grid)
__launch_bounds__(256)
__global__ void conv_embed(const float* __restrict__ qkv_w, const float* __restrict__ attn_out_w,
                           const float* __restrict__ ff_in_w, const float* __restrict__ ff_out_w,
                           __bf16* __restrict__ wq16, __bf16* __restrict__ wa16,
                           __bf16* __restrict__ wfi16, __bf16* __restrict__ wfo16,
                           float* __restrict__ wsq_qkv, float* __restrict__ wsq_ff,
                           const int* __restrict__ tokens, const float* __restrict__ temb,
                           const float* __restrict__ pemb, const float* __restrict__ gamma,
                           float* __restrict__ x, __bf16* __restrict__ y,
                           float* __restrict__ xs) {
    const int tid = threadIdx.x;
    __shared__ float red[4];

    if (blockIdx.x >= WCONV_PER_LAYER) {
        // ---- embed + layer0 rmsnorm path
        const int i = blockIdx.x - WCONV_PER_LAYER;
        int tok = tokens[i];
        const float* e = temb + (size_t)tok * DIMM;
        const float* pp = pemb + (size_t)i * DIMM;
        float v0 = e[tid] + pp[tid];
        float v1 = e[tid + 256] + pp[tid + 256];
        x[(size_t)i * DIMM + tid]       = v0;
        x[(size_t)i * DIMM + tid + 256] = v1;
        float ss = v0 * v0 + v1 * v1;
        #pragma unroll
        for (int off = 32; off; off >>= 1) ss += __shfl_down(ss, off, 64);
        if ((tid & 63) == 0) red[tid >> 6] = ss;
        __syncthreads();
        float tot = red[0] + red[1] + red[2] + red[3];
        float scale = 22.627416997969522f / fmaxf(sqrtf(tot), 1e-12f);
        float y0 = v0 * scale * (gamma[tid] + 1.0f);
        float y1 = v1 * scale * (gamma[tid + 256] + 1.0f);
        y[(size_t)i * DIMM + tid]       = (__bf16)y0;
        y[(size_t)i * DIMM + tid + 256] = (__bf16)y1;
        float s2 = y0 * y0 + y1 * y1;
        __syncthreads();
        #pragma unroll
        for (int off = 32; off; off >>= 1) s2 += __shfl_down(s2, off, 64);
        if ((tid & 63) == 0) red[tid >> 6] = s2;
        __syncthreads();
        if (tid == 0) xs[i] = red[0] + red[1] + red[2] + red[3];
        return;
    }

    conv_weight_row<256>(blockIdx.x, 0, qkv_w, attn_out_w, ff_in_w, ff_out_w,
                         wq16, wa16, wfi16, wfo16, wsq_qkv, wsq_ff, red);
}

// ---------------------------------------------------------------- split-K reduce + residual + rmsnorm (fused)
template<int S>
__launch_bounds__(256)
__global__ void rms_red(const float* __restrict__ parts, float* __restrict__ x,
                        const float* __restrict__ gamma,
                        __bf16* __restrict__ y, float* __restrict__ xs) {
    int i = blockIdx.x;
    int tid = threadIdx.x;
    float* xr = x + (size_t)i * DIMM;
    float v0 = xr[tid], v1 = xr[tid + 256];
    #pragma unroll
    for (int s = 0; s < S; s++) {
        const float* pr = parts + (size_t)s * NSEQ * DIMM + (size_t)i * DIMM;
        v0 += pr[tid];
        v1 += pr[tid + 256];
    }
    xr[tid] = v0;
    xr[tid + 256] = v1;
    float ss = v0 * v0 + v1 * v1;
    __shared__ float red[4];
    #pragma unroll
    for (int off = 32; off; off >>= 1) ss += __shfl_down(ss, off, 64);
    if ((tid & 63) == 0) red[tid >> 6] = ss;
    __syncthreads();
    float tot = red[0] + red[1] + red[2] + red[3];
    float scale = 22.627416997969522f / fmaxf(sqrtf(tot), 1e-12f);
    float y0 = v0 * scale * (gamma[tid] + 1.0f);
    float y1 = v1 * scale * (gamma[tid + 256] + 1.0f);
    y[(size_t)i * DIMM + tid]       = (__bf16)y0;
    y[(size_t)i * DIMM + tid + 256] = (__bf16)y1;
    float s2 = y0 * y0 + y1 * y1;
    __syncthreads();
    #pragma unroll
    for (int off = 32; off; off >>= 1) s2 += __shfl_down(s2, off, 64);
    if ((tid & 63) == 0) red[tid >> 6] = s2;
    __syncthreads();
    if (tid == 0) xs[i] = red[0] + red[1] + red[2] + red[3];
}

enum { MODE_LINEAR = 0, MODE_CDIST = 1, MODE_FFGELU = 2, MODE_LOGITS = 3 };

template<int MODE>
__device__ __forceinline__ void write_elem(void* Cout, int r, int c, int M, float dot,
                                           float xsr, const float* __restrict__ ws,
                                           const float* __restrict__ bias) {
    if (MODE == MODE_LINEAR) {
        ((float*)Cout)[(size_t)r * M + c] = dot;
    } else if (MODE == MODE_FFGELU) {
        float d2 = xsr + ws[c] - 2.0f * dot;
        float hh = -d2 + bias[c];
        float v = 0.5f * hh * (1.0f + erff(hh * 0.70710678118654752f));
        ((__bf16*)Cout)[(size_t)r * M + c] = (__bf16)v;
    }
}

// ---------------------------------------------------------------- logits GEMM, 128x256 tile, 512 thr
// 6 chunk-buffers (3 pairs), two BK=32 chunks/phase, counted vmcnt.
// Epilogue: acc -> swizzled f32 LDS tile -> coalesced nontemporal float4 row writes.
__launch_bounds__(512)
__global__ void gemm_logits(const __bf16* __restrict__ A, const __bf16* __restrict__ W,
                            const float* __restrict__ xs, const float* __restrict__ ws,
                            float* __restrict__ out) {
    __shared__ __align__(16) char smem[49152 + 98304];   // As(48K) | Bs(96K); reused as f32 tile(128K)
    __bf16* As = (__bf16*)smem;
    __bf16* Bs = (__bf16*)(smem + 49152);
    float* tile = (float*)smem;
    const int tid = threadIdx.x;            // 0..511
    const int lane = tid & 63;
    const int wv = tid >> 6;                // 0..7
    const int wr = wv >> 2, wc = wv & 3;    // 2 x 4 waves

    int id = blockIdx.x;                    // 1000 blocks
    id = (id & 7) * 125 + (id >> 3);
    const int row0 = (id & 7) * 128;
    const int col0 = (id >> 3) * 256;

    const int scol = ((tid & 3) ^ ((tid >> 3) & 3)) * 8;
    const __bf16* gA = A + (size_t)(row0 + (tid >> 2)) * DIMM + scol;
    const __bf16* gB = W + (size_t)(col0 + (tid >> 2)) * DIMM + scol;
    const int lrow = lane & 15;
    const int l4 = lane >> 4;
    const int slot = (l4 ^ ((lrow >> 1) & 3)) * 8;

    auto stageChunk = [&](int k0, int b) {       // 3 loads/thread/chunk
        g2l16(gA + k0,                      As + b * 4096 + tid * 8);
        g2l16(gB + k0,                      Bs + b * 8192 + tid * 8);
        g2l16(gB + (size_t)128 * DIMM + k0, Bs + b * 8192 + 4096 + tid * 8);
    };

    f32x4 acc[4][4] = {};
    const int nP = DIMM >> 6;               // 8 pair-phases
    stageChunk(0, 0);  stageChunk(32, 1);
    stageChunk(64, 2); stageChunk(96, 3);
    int pb = 0;
    for (int p = 0; p < nP; p++) {
        if (p < nP - 1) WAITV(6); else WAITV(0);
        __builtin_amdgcn_s_barrier();
        __builtin_amdgcn_sched_barrier(0);
        if (p + 2 < nP) {
            int nb = pb + 2; if (nb >= 3) nb -= 3;
            stageChunk((p + 2) << 6,        nb * 2);
            stageChunk(((p + 2) << 6) + 32, nb * 2 + 1);
        }
        #pragma unroll
        for (int half = 0; half < 2; half++) {
            const int b = pb * 2 + half;
            bf16x8 af[4], bfr[4];
            #pragma unroll
            for (int m = 0; m < 4; m++)
                af[m] = *(const bf16x8*)(As + b * 4096 + (wr * 64 + m * 16 + lrow) * 32 + slot);
            #pragma unroll
            for (int n = 0; n < 4; n++)
                bfr[n] = *(const bf16x8*)(Bs + b * 8192 + (wc * 64 + n * 16 + lrow) * 32 + slot);
            #pragma unroll
            for (int m = 0; m < 4; m++)
                #pragma unroll
                for (int n = 0; n < 4; n++)
                    acc[m][n] = __builtin_amdgcn_mfma_f32_16x16x32_bf16(af[m], bfr[n], acc[m][n], 0, 0, 0);
        }
        if (++pb == 3) pb = 0;
    }
    __syncthreads();   // staging LDS dead; safe to reuse as f32 tile

    #pragma unroll
    for (int m = 0; m < 4; m++)
        #pragma unroll
        for (int j = 0; j < 4; j++) {
            const int rl = wr * 64 + m * 16 + l4 * 4 + j;
            const float xsr = xs[row0 + rl];
            const int sw = ((rl >> 2) & 3) << 2;
            #pragma unroll
            for (int n = 0; n < 4; n++) {
                const int cl = wc * 64 + n * 16 + lrow;
                tile[rl * 256 + (cl ^ sw)] = -(xsr + ws[col0 + cl] - 2.0f * acc[m][n][j]);
            }
        }
    __syncthreads();

    #pragma unroll
    for (int jj = 0; jj < 16; jj++) {
        const int f = jj * 2048 + tid * 4;
        const int rr = f >> 8, cc = f & 255;
        const int sw = ((rr >> 2) & 3) << 2;
        f32x4 v = *(const f32x4*)&tile[rr * 256 + (cc ^ sw)];
        __builtin_nontemporal_store(v, (f32x4*)&out[(size_t)(row0 + rr) * NVOC + col0 + cc]);
    }
}

// ---------------------------------------------------------------- MFMA GEMM, 64x64 tile
// 6 chunk-buffers (3 pairs), two BK=32 chunks per barrier phase, counted vmcnt.
template<int MODE>
__launch_bounds__(256)
__global__ void gemm64(const __bf16* __restrict__ A, const __bf16* __restrict__ W,
                       const float* __restrict__ xs, const float* __restrict__ ws,
                       const float* __restrict__ bias,
                       void* __restrict__ Cout, int K, int Kstr, int M,
                       float* __restrict__ ksout) {
    __shared__ __align__(16) __bf16 As[6 * 64 * 32];   // 24 KB
    __shared__ __align__(16) __bf16 Bs[6 * 64 * 32];   // 24 KB
    __shared__ float ksred[2][64];
    const int tid = threadIdx.x;
    const int lane = tid & 63;
    const int wv = tid >> 6;
    const int wr = wv >> 1, wc = wv & 1;

    const int gx = gridDim.x;
    const int total = gx * gridDim.y;
    int id = blockIdx.y * gx + blockIdx.x;
    id = (id & 7) * (total >> 3) + (id >> 3);
    const int bx = id % gx;
    const int by = id / gx;
    const int row0 = by * 64;
    const int col0 = bx * 64;
    const size_t zoff = (size_t)blockIdx.z * K;
    float* Cz = (float*)Cout + (size_t)blockIdx.z * NSEQ * M;

    const int scol = (((tid & 3) ^ ((tid >> 3) & 3))) * 8;
    const __bf16* gA = A + (size_t)(row0 + (tid >> 2)) * Kstr + scol + zoff;
    const __bf16* gB = W + (size_t)(col0 + (tid >> 2)) * Kstr + scol + zoff;
    const int lrow = lane & 15;
    const int l4 = lane >> 4;
    const int slot = (l4 ^ ((lrow >> 1) & 3)) * 8;

    auto stageChunk = [&](int k0, int b) {   // 2 loads/thread/chunk
        g2l16(gA + k0, &As[b * 2048 + tid * 8]);
        g2l16(gB + k0, &Bs[b * 2048 + tid * 8]);
    };

    f32x4 acc[2][2] = {};
    const int nP = K >> 6;          // pair-phases
    stageChunk(0, 0);  stageChunk(32, 1);
    stageChunk(64, 2); stageChunk(96, 3);
    int pb = 0;
    for (int p = 0; p < nP; p++) {
        if (p < nP - 1) WAITV(4); else WAITV(0);
        __builtin_amdgcn_s_barrier();
        __builtin_amdgcn_sched_barrier(0);
        if (p + 2 < nP) {
            int nb = pb + 2; if (nb >= 3) nb -= 3;
            stageChunk((p + 2) << 6,        nb * 2);
            stageChunk(((p + 2) << 6) + 32, nb * 2 + 1);
        }
        #pragma unroll
        for (int half = 0; half < 2; half++) {
            const int b = pb * 2 + half;
            bf16x8 af[2], bfr[2];
            #pragma unroll
            for (int m = 0; m < 2; m++)
                af[m] = *(const bf16x8*)&As[b * 2048 + (wr * 32 + m * 16 + lrow) * 32 + slot];
            #pragma unroll
            for (int n = 0; n < 2; n++)
                bfr[n] = *(const bf16x8*)&Bs[b * 2048 + (wc * 32 + n * 16 + lrow) * 32 + slot];
            #pragma unroll
            for (int m = 0; m < 2; m++)
                #pragma unroll
                for (int n = 0; n < 2; n++)
                    acc[m][n] = __builtin_amdgcn_mfma_f32_16x16x32_bf16(af[m], bfr[n], acc[m][n], 0, 0, 0);
        }
        if (++pb == 3) pb = 0;
    }

    const int r_base = row0 + wr * 32 + (lane >> 4) * 4;
    const int c_base = col0 + wc * 32 + (lane & 15);

    if (MODE == MODE_CDIST) {
        const int sec = col0 >> 9;          // 0=q,1=k,2=v (uniform per block)
        const int h = (col0 >> 6) & 7;
        __bf16* Qc = (__bf16*)Cout;
        float pk[2][4];
        #pragma unroll
        for (int m = 0; m < 2; m++)
            #pragma unroll
            for (int j = 0; j < 4; j++) {
                const int r = r_base + m * 16 + j;
                const float xsr = xs[r];
                pk[m][j] = 0.f;
                #pragma unroll
                for (int n = 0; n < 2; n++) {
                    const int c = c_base + n * 16;
                    float d2 = xsr + ws[c] - 2.0f * acc[m][n][j];
                    float v = sqrtf(fmaxf(d2, 0.0f)) - VCENTER;
                    __bf16 bv = (__bf16)v;
                    const int d = c & 63;
                    if (sec == 0)      Qc[((size_t)h * NSEQ + r) * DH + d] = bv;
                    else if (sec == 1) Qc[QKOFF + ((size_t)h * NSEQ + r) * DH + d] = bv;
                    else               Qc[2 * QKOFF + ((size_t)h * DH + d) * NSEQ + r] = bv;
                    float fv = (float)bv;
                    pk[m][j] += fv * fv;
                }
            }
        if (sec == 1) {
            #pragma unroll
            for (int m = 0; m < 2; m++)
                #pragma unroll
                for (int j = 0; j < 4; j++) {
                    float v = pk[m][j];
                    #pragma unroll
                    for (int off = 1; off < 16; off <<= 1) v += __shfl_xor(v, off, 64);
                    if (lrow == 0) ksred[wc][wr * 32 + m * 16 + l4 * 4 + j] = v;
                }
            __syncthreads();
            if (tid < 64)
                ksout[(size_t)h * NSEQ + row0 + tid] = ksred[0][tid] + ksred[1][tid];
        }
    } else {
        #pragma unroll
        for (int m = 0; m < 2; m++)
            #pragma unroll
            for (int j = 0; j < 4; j++) {
                const int r = r_base + m * 16 + j;
                const float xsr = (MODE == MODE_LINEAR) ? 0.f : xs[r];
                #pragma unroll
                for (int n = 0; n < 2; n++)
                    write_elem<MODE>(Cz, r, c_base + n * 16, M, acc[m][n][j], xsr, ws, bias);
            }
    }
}

// ---------------------------------------------------------------- flash attention + temb conversion + (layer-0 only)
// next-layer weight conversion, all in one grid:
// [0,256): flash; [256,506): temb rows; [506, 506+4608): layer-1 weight rows
__launch_bounds__(128)
__global__ void flash_attn(const __bf16* __restrict__ Qc, const __bf16* __restrict__ Kc,
                           const __bf16* __restrict__ VcT, const float* __restrict__ ks,
                           __bf16* __restrict__ O,
                           const float* __restrict__ temb, __bf16* __restrict__ temb16,
                           float* __restrict__ wsq_temb, int conv_row0,
                           const float* __restrict__ qkv_w, const float* __restrict__ attn_out_w,
                           const float* __restrict__ ff_in_w, const float* __restrict__ ff_out_w,
                           __bf16* __restrict__ wq16, __bf16* __restrict__ wa16,
                           __bf16* __restrict__ wfi16, __bf16* __restrict__ wfo16,
                           float* __restrict__ wsq_qkv, float* __restrict__ wsq_ff) {
    const int tid = threadIdx.x, lane = tid & 63, wv = tid >> 6;

    if (blockIdx.x >= FLASH_BLOCKS + CONV_BLOCKS) {
        // ---- next-layer weight conversion (present only in layer-0 launch)
        __shared__ float redc[2];
        conv_weight_row<128>(blockIdx.x - FLASH_BLOCKS - CONV_BLOCKS, 1,
                             qkv_w, attn_out_w, ff_in_w, ff_out_w,
                             wq16, wa16, wfi16, wfo16, wsq_qkv, wsq_ff, redc);
        return;
    }
    if (blockIdx.x >= FLASH_BLOCKS) {
        // ---- temb conversion path: 64 rows/block
        const int base = conv_row0 + (blockIdx.x - FLASH_BLOCKS) * 64;
        for (int it = 0; it < 32; it++) {
            const int row = base + it * 2 + wv;
            const float* src = temb + (size_t)row * DIMM;
            float4 a = ((const float4*)src)[lane];
            float4 b2 = ((const float4*)src)[lane + 64];
            float ss = a.x * a.x + a.y * a.y + a.z * a.z + a.w * a.w
                     + b2.x * b2.x + b2.y * b2.y + b2.z * b2.z + b2.w * b2.w;
            bf16x4 oa, ob;
            oa.x = (__bf16)a.x;  oa.y = (__bf16)a.y;  oa.z = (__bf16)a.z;  oa.w = (__bf16)a.w;
            ob.x = (__bf16)b2.x; ob.y = (__bf16)b2.y; ob.z = (__bf16)b2.z; ob.w = (__bf16)b2.w;
            *(bf16x4*)&temb16[(size_t)row * DIMM + lane * 4]       = oa;
            *(bf16x4*)&temb16[(size_t)row * DIMM + 256 + lane * 4] = ob;
            #pragma unroll
            for (int off = 32; off; off >>= 1) ss += __shfl_down(ss, off, 64);
            if (lane == 0) wsq_temb[row] = ss;
        }
        return;
    }

    __shared__ __align__(16) __bf16 Qs[QBLK * 64];
    __shared__ __align__(16) __bf16 Ks[2][64 * 64];
    __shared__ __align__(16) __bf16 Vs[2][64 * 64];
    __shared__ __align__(16) __bf16 Ps[2][16 * 64];
    __shared__ float kss[2][64];
    const int h = blockIdx.x >> 5, q0 = (blockIdx.x & 31) * QBLK;
    const int l15 = lane & 15, l4 = lane >> 4;

    #pragma unroll
    for (int pass = 0; pass < 2; pass++) {
        int gl = tid + pass * 128, r = gl >> 3, gs = (gl & 7) ^ (r & 7);
        g2l16(Qc + ((size_t)h * NSEQ + q0 + r) * DH + gs * 8, &Qs[gl * 8]);
    }
    auto stage = [&](int c, int buf) {
        const int kv0 = c * KVB;
        #pragma unroll
        for (int pass = 0; pass < 4; pass++) {
            int gl = tid + pass * 128, r = gl >> 3, gs = (gl & 7) ^ (r & 7);
            g2l16(Kc + ((size_t)h * NSEQ + kv0 + r) * DH + gs * 8, &Ks[buf][gl * 8]);
            g2l16(VcT + ((size_t)h * DH + r) * NSEQ + kv0 + gs * 8, &Vs[buf][gl * 8]);
        }
        if (tid < KVB) kss[buf][tid] = ks[(size_t)h * NSEQ + c * KVB + tid];
    };
    stage(0, 0);
    __syncthreads();

    bf16x8 qf[2];
    #pragma unroll
    for (int s = 0; s < 2; s++) {
        int row = wv * 16 + l15;
        int g = (l4 + 4 * s) ^ (row & 7);
        qf[s] = *(const bf16x8*)&Qs[row * 64 + g * 8];
    }

    float m_j[4], l_j[4];
    f32x4 o_[4] = {};
    #pragma unroll
    for (int j = 0; j < 4; j++) { m_j[j] = -1e30f; l_j[j] = 0.f; }

    for (int c = 0; c < NSEQ / KVB; c++) {
        const int b = c & 1;
        if (c + 1 < NSEQ / KVB) stage(c + 1, b ^ 1);

        f32x4 sa[4] = {};
        #pragma unroll
        for (int s = 0; s < 2; s++) {
            bf16x8 kf[4];
            #pragma unroll
            for (int n = 0; n < 4; n++) {
                int row = n * 16 + l15;
                int g = (l4 + 4 * s) ^ (row & 7);
                kf[n] = *(const bf16x8*)&Ks[b][row * 64 + g * 8];
            }
            #pragma unroll
            for (int n = 0; n < 4; n++)
                sa[n] = __builtin_amdgcn_mfma_f32_16x16x32_bf16(qf[s], kf[n], sa[n], 0, 0, 0);
        }
        float ksv[4];
        #pragma unroll
        for (int n = 0; n < 4; n++) ksv[n] = kss[b][n * 16 + l15];

        float scale[4];
        #pragma unroll
        for (int j = 0; j < 4; j++) {
            float mx = -1e30f;
            #pragma unroll
            for (int n = 0; n < 4; n++) {
                float sv = sa[n][j] * 0.25f - ksv[n] * 0.125f;
                sa[n][j] = sv;
                mx = fmaxf(mx, sv);
            }
            #pragma unroll
            for (int off = 1; off < 16; off <<= 1) mx = fmaxf(mx, __shfl_xor(mx, off, 64));
            float mn = fmaxf(m_j[j], mx);
            scale[j] = expf(m_j[j] - mn);
            m_j[j] = mn;
        }
        #pragma unroll
        for (int j = 0; j < 4; j++) {
            const int row = l4 * 4 + j;
            float ls = 0.f;
            #pragma unroll
            for (int n = 0; n < 4; n++) {
                float pv = expf(sa[n][j] - m_j[j]);
                ls += pv;
                int col = n * 16 + l15;
                Ps[wv][row * 64 + ((((col >> 3) ^ (row & 7)) << 3) | (col & 7))] = (__bf16)pv;
            }
            #pragma unroll
            for (int off = 1; off < 16; off <<= 1) ls += __shfl_xor(ls, off, 64);
            l_j[j] = l_j[j] * scale[j] + ls;
            o_[0][j] *= scale[j]; o_[1][j] *= scale[j];
            o_[2][j] *= scale[j]; o_[3][j] *= scale[j];
        }

        #pragma unroll
        for (int s = 0; s < 2; s++) {
            int g = (l4 + 4 * s) ^ (l15 & 7);
            bf16x8 pf = *(const bf16x8*)&Ps[wv][l15 * 64 + g * 8];
            #pragma unroll
            for (int n = 0; n < 4; n++) {
                int row = n * 16 + l15;
                int gv = (l4 + 4 * s) ^ (row & 7);
                bf16x8 vf = *(const bf16x8*)&Vs[b][row * 64 + gv * 8];
                o_[n] = __builtin_amdgcn_mfma_f32_16x16x32_bf16(pf, vf, o_[n], 0, 0, 0);
            }
        }
        __syncthreads();
    }

    #pragma unroll
    for (int n = 0; n < 4; n++)
        #pragma unroll
        for (int j = 0; j < 4; j++) {
            int row = q0 + wv * 16 + l4 * 4 + j;
            int d = n * 16 + l15;
            O[(size_t)row * DIMM + h * DH + d] = (__bf16)(o_[n][j] / l_j[j] + VCENTER);
        }
}

// ---------------------------------------------------------------- launch
extern "C" void kernel_launch(void* const* d_in, const int* in_sizes, int n_in,
                              void* d_out, int out_size, void* d_ws, size_t ws_size,
                              hipStream_t stream) {
    (void)in_sizes; (void)n_in; (void)out_size; (void)ws_size;
    const int*   tokens      = (const int*)d_in[0];
    const float* temb        = (const float*)d_in[1];
    const float* pemb        = (const float*)d_in[2];
    const float* qkv_w       = (const float*)d_in[3];
    const float* attn_out_w  = (const float*)d_in[4];
    const float* ff_in_w     = (const float*)d_in[5];
    const float* ff_in_b     = (const float*)d_in[6];
    const float* ff_out_w    = (const float*)d_in[7];
    const float* attn_gamma  = (const float*)d_in[8];
    const float* ff_gamma    = (const float*)d_in[9];
    const float* final_gamma = (const float*)d_in[10];
    float* out = (float*)d_out;

    char* p = (char*)d_ws;
    float*  x        = (float*)p;  p += (size_t)NSEQ * DIMM * 4;
    float*  xs       = (float*)p;  p += (size_t)NSEQ * 4;
    float*  wsq_qkv  = (float*)p;  p += (size_t)NDEPTH * 3 * DIMM * 4;
    float*  wsq_ff   = (float*)p;  p += (size_t)NDEPTH * DFF * 4;
    float*  wsq_temb = (float*)p;  p += (size_t)NVOC * 4;
    float*  ksbuf    = (float*)p;  p += (size_t)NHEAD * NSEQ * 4;
    float*  parts    = (float*)p;  p += (size_t)4 * NSEQ * DIMM * 4;   // split-K partials (8 MB)
    __bf16* y16      = (__bf16*)p; p += (size_t)NSEQ * DIMM * 2;
    __bf16* o16      = (__bf16*)p; p += (size_t)NSEQ * DIMM * 2;
    __bf16* Qc       = (__bf16*)p; p += 3 * QKOFF * 2;        // Qc | Kc | VcT
    __bf16* hb16     = (__bf16*)p; p += (size_t)NSEQ * DFF * 2;
    __bf16* wq16     = (__bf16*)p; p += (size_t)NDEPTH * 3 * DIMM * DIMM * 2;
    __bf16* wa16     = (__bf16*)p; p += (size_t)NDEPTH * DIMM * DIMM * 2;
    __bf16* wfi16    = (__bf16*)p; p += (size_t)NDEPTH * DFF * DIMM * 2;
    __bf16* wfo16    = (__bf16*)p; p += (size_t)NDEPTH * DIMM * DFF * 2;
    __bf16* temb16   = (__bf16*)p; p += (size_t)NVOC * DIMM * 2;
    __bf16* Kc  = Qc + QKOFF;
    __bf16* VcT = Qc + 2 * QKOFF;

    conv_embed<<<WCONV_PER_LAYER + NSEQ, 256, 0, stream>>>(
        qkv_w, attn_out_w, ff_in_w, ff_out_w,
        wq16, wa16, wfi16, wfo16, wsq_qkv, wsq_ff,
        tokens, temb, pemb, attn_gamma, x, y16, xs);

    for (int l = 0; l < NDEPTH; l++) {
        const __bf16* qkvw = wq16  + (size_t)l * 3 * DIMM * DIMM;
        const __bf16* aow  = wa16  + (size_t)l * DIMM * DIMM;
        const __bf16* fiw  = wfi16 + (size_t)l * DFF * DIMM;
        const __bf16* fow  = wfo16 + (size_t)l * DIMM * DFF;
        const float*  fib  = ff_in_b + (size_t)l * DFF;
        const float*  next_gamma = (l + 1 < NDEPTH) ? (attn_gamma + (l + 1) * DIMM)
                                                    : final_gamma;

        gemm64<MODE_CDIST><<<dim3(3 * DIMM / 64, NSEQ / 64), 256, 0, stream>>>(
            y16, qkvw, xs, wsq_qkv + l * 3 * DIMM, nullptr, Qc, DIMM, DIMM, 3 * DIMM, ksbuf);
        // layer 0's flash also converts layer-1 weights + first half of temb
        const int flashGrid = FLASH_BLOCKS + CONV_BLOCKS + ((l == 0) ? WCONV_PER_LAYER : 0);
        flash_attn<<<flashGrid, 128, 0, stream>>>(
            Qc, Kc, VcT, ksbuf, o16, temb, temb16, wsq_temb, l * CONV_ROWS_PER_LAYER,
            qkv_w, attn_out_w, ff_in_w, ff_out_w,
            wq16, wa16, wfi16, wfo16, wsq_qkv, wsq_ff);
        gemm64<MODE_LINEAR><<<dim3(DIMM / 64, NSEQ / 64, 2), 256, 0, stream>>>(
            o16, aow, nullptr, nullptr, nullptr, parts, DIMM / 2, DIMM, DIMM, nullptr);
        rms_red<2><<<NSEQ, 256, 0, stream>>>(parts, x, ff_gamma + l * DIMM, y16, xs);

        gemm64<MODE_FFGELU><<<dim3(DFF / 64, NSEQ / 64), 256, 0, stream>>>(
            y16, fiw, xs, wsq_ff + l * DFF, fib, hb16, DIMM, DIMM, DFF, nullptr);
        gemm64<MODE_LINEAR><<<dim3(DIMM / 64, NSEQ / 64, 4), 256, 0, stream>>>(
            hb16, fow, nullptr, nullptr, nullptr, parts, DFF / 4, DFF, DIMM, nullptr);
        rms_red<4><<<NSEQ, 256, 0, stream>>>(parts, x, next_gamma, y16, xs);
    }

    gemm_logits<<<1000, 512, 0, stream>>>(y16, temb16, xs, wsq_temb, out);
}